// Round 2
// baseline (518.984 us; speedup 1.0000x reference)
//
#include <hip/hip_runtime.h>
#include <math.h>

#define FEAT 64
#define NKERN 3
#define WT_STRIDE 196   // 192 + 4; 196 % 32 == 4 -> uniform bank spread for b128

// Aggregate: g[n, k*64+j] = sum_{e in row(n)} w[e,k] * h[colind[e], j]
// One wave per node, lane = feature. deg==32 path is fully unrolled with all
// 32 gather loads hoisted (phase 1) before the shfl/FMA consume phase (phase 2)
// so the wave keeps 32 vmem loads in flight.
__global__ __launch_bounds__(256) void agg_kernel(
    const float* __restrict__ h,       // [N, 64]
    const float* __restrict__ pseudo,  // [E, 2]
    const int*   __restrict__ rowptr,  // [N+1]
    const int*   __restrict__ colind,  // [E]
    const float* __restrict__ projW,   // [2,2] this layer (din,dout)
    const float* __restrict__ projB,   // [2]
    const float* __restrict__ mu,      // [3,2]
    const float* __restrict__ isg,     // [3,2]
    float* __restrict__ g,             // [N, 192]
    int n_nodes)
{
    int lane = threadIdx.x & 63;
    int node = (int)((blockIdx.x * blockDim.x + threadIdx.x) >> 6);
    if (node >= n_nodes) return;
    int nu = __builtin_amdgcn_readfirstlane(node);
    int r0 = rowptr[nu];
    int r1 = rowptr[nu + 1];
    int deg = r1 - r0;   // fixed 32 in this problem

    float w0 = 0.f, w1 = 0.f, w2 = 0.f;
    int c = 0;
    if (lane < deg) {
        int e = r0 + lane;
        float p0 = pseudo[2 * e];
        float p1 = pseudo[2 * e + 1];
        float u0 = tanhf(fmaf(p0, projW[0], fmaf(p1, projW[2], projB[0])));
        float u1 = tanhf(fmaf(p0, projW[1], fmaf(p1, projW[3], projB[1])));
        float d0, d1, s0, s1;
        d0 = u0 - mu[0]; d1 = u1 - mu[1]; s0 = isg[0]; s1 = isg[1];
        w0 = expf(-0.5f * (d0*d0*s0*s0 + d1*d1*s1*s1));
        d0 = u0 - mu[2]; d1 = u1 - mu[3]; s0 = isg[2]; s1 = isg[3];
        w1 = expf(-0.5f * (d0*d0*s0*s0 + d1*d1*s1*s1));
        d0 = u0 - mu[4]; d1 = u1 - mu[5]; s0 = isg[4]; s1 = isg[5];
        w2 = expf(-0.5f * (d0*d0*s0*s0 + d1*d1*s1*s1));
        c = colind[e];
    }

    float a0 = 0.f, a1 = 0.f, a2 = 0.f;
    if (deg == 32) {
        float v[32];
        // Phase 1: issue all 32 coalesced 256B gathers back-to-back.
        #pragma unroll
        for (int e = 0; e < 32; ++e) {
            int cc = __shfl(c, e);                 // literal lane -> v_readlane
            v[e] = h[(size_t)cc * FEAT + lane];
        }
        // Phase 2: consume (compiler interleaves with decreasing vmcnt).
        #pragma unroll
        for (int e = 0; e < 32; ++e) {
            float ww0 = __shfl(w0, e);
            float ww1 = __shfl(w1, e);
            float ww2 = __shfl(w2, e);
            a0 = fmaf(ww0, v[e], a0);
            a1 = fmaf(ww1, v[e], a1);
            a2 = fmaf(ww2, v[e], a2);
        }
    } else {
        for (int e = 0; e < deg; ++e) {
            int   cc  = __shfl(c, e);
            float ww0 = __shfl(w0, e);
            float ww1 = __shfl(w1, e);
            float ww2 = __shfl(w2, e);
            float v = h[(size_t)cc * FEAT + lane];
            a0 = fmaf(ww0, v, a0);
            a1 = fmaf(ww1, v, a1);
            a2 = fmaf(ww2, v, a2);
        }
    }
    float* gp = g + (size_t)node * (NKERN * FEAT);
    gp[lane]            = a0;
    gp[FEAT + lane]     = a1;
    gp[2 * FEAT + lane] = a2;
}

// out[n, f] = sum_{jp=0..191} g[n, jp] * Wcat[jp, f],
// Wcat[k*64+j, f] = fc_W[j, k*64+f]. W kept TRANSPOSED in LDS:
// Wt[f][jp] with stride 196 so each lane (f = lane) reads its own column
// contiguously via ds_read_b128. 8 rows per wave -> 1536 FMA per 48 LDS reads.
__global__ __launch_bounds__(256) void gemm_kernel(
    const float* __restrict__ g,    // [N, 192]
    const float* __restrict__ fcW,  // [64, 192] this layer
    float* __restrict__ out,        // [N, 64]
    int n_nodes)
{
    __shared__ float Wt[FEAT * WT_STRIDE];  // ~49 KB
    int tid = threadIdx.x;
    for (int i = tid; i < FEAT * 192; i += 256) {
        int f  = i / 192;
        int jp = i - f * 192;
        Wt[f * WT_STRIDE + jp] = fcW[(jp & 63) * 192 + (jp >> 6) * 64 + f];
    }
    __syncthreads();

    int lane   = tid & 63;
    int wave   = (int)((blockIdx.x * 256 + tid) >> 6);
    int nwaves = gridDim.x * 4;
    int nchunk = (n_nodes + 7) >> 3;
    const float* wcol = &Wt[lane * WT_STRIDE];

    for (int ch = wave; ch < nchunk; ch += nwaves) {
        int row0 = __builtin_amdgcn_readfirstlane(ch << 3);
        int nr = n_nodes - row0; if (nr > 8) nr = 8;
        const float* grow = g + (size_t)row0 * 192;
        if (nr == 8) {
            float acc[8] = {0.f,0.f,0.f,0.f,0.f,0.f,0.f,0.f};
            #pragma unroll 4
            for (int j = 0; j < 192; j += 4) {
                float4 wv = *(const float4*)&wcol[j];
                #pragma unroll
                for (int r = 0; r < 8; ++r) {
                    const float* gr = grow + r * 192 + j;
                    float t0 = fmaf(gr[0], wv.x, acc[r]);
                    float t1 = fmaf(gr[1], wv.y, t0);
                    float t2 = fmaf(gr[2], wv.z, t1);
                    acc[r]   = fmaf(gr[3], wv.w, t2);
                }
            }
            #pragma unroll
            for (int r = 0; r < 8; ++r)
                out[(size_t)(row0 + r) * 64 + lane] = acc[r];
        } else {
            for (int r = 0; r < nr; ++r) {
                float acc = 0.f;
                for (int j = 0; j < 192; ++j)
                    acc = fmaf(grow[r * 192 + j], wcol[j], acc);
                out[(size_t)(row0 + r) * 64 + lane] = acc;
            }
        }
    }
}

extern "C" void kernel_launch(void* const* d_in, const int* in_sizes, int n_in,
                              void* d_out, int out_size, void* d_ws, size_t ws_size,
                              hipStream_t stream)
{
    const float* feat   = (const float*)d_in[0];   // [N, 64]
    const float* pseudo = (const float*)d_in[1];   // [E, 2]
    const int*   rowptr = (const int*)d_in[2];     // [N+1]
    const int*   colind = (const int*)d_in[3];     // [E]
    const float* projW  = (const float*)d_in[4];   // [L, 2, 2]
    const float* projB  = (const float*)d_in[5];   // [L, 2]
    const float* fcW    = (const float*)d_in[6];   // [L, 64, 192]
    const float* mu     = (const float*)d_in[7];   // [L, 3, 2]
    const float* isg    = (const float*)d_in[8];   // [L, 3, 2]
    float* out = (float*)d_out;

    int n = in_sizes[0] / FEAT;                         // 50000
    int n_layers = in_sizes[6] / (FEAT * NKERN * FEAT); // 3

    float* gbuf = (float*)d_ws;                    // n * 192 floats
    float* hbuf = gbuf + (size_t)n * NKERN * FEAT; // n * 64 floats

    dim3 blk(256);
    dim3 aggGrid((n + 3) / 4);
    dim3 gemmGrid(1024);

    const float* hin = feat;
    for (int l = 0; l < n_layers; ++l) {
        float* hout = (l == n_layers - 1) ? out : hbuf;
        agg_kernel<<<aggGrid, blk, 0, stream>>>(
            hin, pseudo, rowptr, colind,
            projW + (size_t)l * 4, projB + (size_t)l * 2,
            mu + (size_t)l * 6, isg + (size_t)l * 6,
            gbuf, n);
        gemm_kernel<<<gemmGrid, blk, 0, stream>>>(
            gbuf, fcW + (size_t)l * FEAT * NKERN * FEAT, hout, n);
        hin = hbuf;
    }
}

// Round 3
// 370.949 us; speedup vs baseline: 1.3991x; 1.3991x over previous
//
#include <hip/hip_runtime.h>
#include <math.h>

#define FEAT 64
#define NKERN 3

// Aggregate: g[n, k*64+j] = sum_{e in row(n)} w[e,k] * h[colind[e], j]
// One wave per node, lane = feature. deg==32 path fully unrolled with all
// 32 gather loads hoisted so the wave keeps 32 vmem loads in flight.
__global__ __launch_bounds__(256) void agg_kernel(
    const float* __restrict__ h,       // [N, 64]
    const float* __restrict__ pseudo,  // [E, 2]
    const int*   __restrict__ rowptr,  // [N+1]
    const int*   __restrict__ colind,  // [E]
    const float* __restrict__ projW,   // [2,2] this layer (din,dout)
    const float* __restrict__ projB,   // [2]
    const float* __restrict__ mu,      // [3,2]
    const float* __restrict__ isg,     // [3,2]
    float* __restrict__ g,             // [N, 192]
    int n_nodes)
{
    int lane = threadIdx.x & 63;
    int node = (int)((blockIdx.x * blockDim.x + threadIdx.x) >> 6);
    if (node >= n_nodes) return;
    int nu = __builtin_amdgcn_readfirstlane(node);
    int r0 = rowptr[nu];
    int r1 = rowptr[nu + 1];
    int deg = r1 - r0;   // fixed 32 in this problem

    float w0 = 0.f, w1 = 0.f, w2 = 0.f;
    int c = 0;
    if (lane < deg) {
        int e = r0 + lane;
        float p0 = pseudo[2 * e];
        float p1 = pseudo[2 * e + 1];
        float u0 = tanhf(fmaf(p0, projW[0], fmaf(p1, projW[2], projB[0])));
        float u1 = tanhf(fmaf(p0, projW[1], fmaf(p1, projW[3], projB[1])));
        float d0, d1, s0, s1;
        d0 = u0 - mu[0]; d1 = u1 - mu[1]; s0 = isg[0]; s1 = isg[1];
        w0 = expf(-0.5f * (d0*d0*s0*s0 + d1*d1*s1*s1));
        d0 = u0 - mu[2]; d1 = u1 - mu[3]; s0 = isg[2]; s1 = isg[3];
        w1 = expf(-0.5f * (d0*d0*s0*s0 + d1*d1*s1*s1));
        d0 = u0 - mu[4]; d1 = u1 - mu[5]; s0 = isg[4]; s1 = isg[5];
        w2 = expf(-0.5f * (d0*d0*s0*s0 + d1*d1*s1*s1));
        c = colind[e];
    }

    float a0 = 0.f, a1 = 0.f, a2 = 0.f;
    if (deg == 32) {
        float v[32];
        #pragma unroll
        for (int e = 0; e < 32; ++e) {
            int cc = __shfl(c, e);
            v[e] = h[(size_t)cc * FEAT + lane];
        }
        #pragma unroll
        for (int e = 0; e < 32; ++e) {
            float ww0 = __shfl(w0, e);
            float ww1 = __shfl(w1, e);
            float ww2 = __shfl(w2, e);
            a0 = fmaf(ww0, v[e], a0);
            a1 = fmaf(ww1, v[e], a1);
            a2 = fmaf(ww2, v[e], a2);
        }
    } else {
        for (int e = 0; e < deg; ++e) {
            int   cc  = __shfl(c, e);
            float ww0 = __shfl(w0, e);
            float ww1 = __shfl(w1, e);
            float ww2 = __shfl(w2, e);
            float v = h[(size_t)cc * FEAT + lane];
            a0 = fmaf(ww0, v, a0);
            a1 = fmaf(ww1, v, a1);
            a2 = fmaf(ww2, v, a2);
        }
    }
    float* gp = g + (size_t)node * (NKERN * FEAT);
    gp[lane]            = a0;
    gp[FEAT + lane]     = a1;
    gp[2 * FEAT + lane] = a2;
}

// out[n, f] = sum_{jp=0..191} g[n, jp] * fcW[jp&63, (jp>>6)*64 + f]
// lane = row (node). Block = 64 rows x 4 waves; wave w covers f in
// [16w, 16w+16) with acc[16] in VGPRs. g: per-lane float4 loads (L1-tiled,
// each 64B g-line reused across its 16 j's). W: wave-uniform addresses
// (fbase forced uniform) -> s_load; FMA consumes the SGPR directly.
// No LDS => no SMEM/LDS lgkmcnt mixing.
__global__ __launch_bounds__(256) void gemm_kernel(
    const float* __restrict__ g,    // [N, 192]
    const float* __restrict__ fcW,  // [64, 192] this layer
    float* __restrict__ out,        // [N, 64]
    int n_nodes)
{
    int lane  = threadIdx.x & 63;
    int fbase = __builtin_amdgcn_readfirstlane((threadIdx.x >> 6) * 16);
    int row   = blockIdx.x * 64 + lane;
    int rowc  = row < n_nodes ? row : n_nodes - 1;   // clamp: loads valid, store guarded
    const float4* grow4 = (const float4*)(g + (size_t)rowc * 192);

    float acc[16];
    #pragma unroll
    for (int i = 0; i < 16; ++i) acc[i] = 0.f;

    #pragma unroll 2
    for (int jp4 = 0; jp4 < 192; jp4 += 4) {
        float4 gv = grow4[jp4 >> 2];
        int k = jp4 >> 6;        // uniform: kernel block
        int j = jp4 & 63;        // uniform: row within fcW
        #pragma unroll
        for (int i = 0; i < 4; ++i) {
            float gvi = (i == 0) ? gv.x : (i == 1) ? gv.y : (i == 2) ? gv.z : gv.w;
            const float* wr = fcW + (size_t)((j + i) * 192 + k * 64 + fbase);
            float4 wa = *(const float4*)(wr + 0);
            float4 wb = *(const float4*)(wr + 4);
            float4 wc = *(const float4*)(wr + 8);
            float4 wd = *(const float4*)(wr + 12);
            acc[0]  = fmaf(gvi, wa.x, acc[0]);
            acc[1]  = fmaf(gvi, wa.y, acc[1]);
            acc[2]  = fmaf(gvi, wa.z, acc[2]);
            acc[3]  = fmaf(gvi, wa.w, acc[3]);
            acc[4]  = fmaf(gvi, wb.x, acc[4]);
            acc[5]  = fmaf(gvi, wb.y, acc[5]);
            acc[6]  = fmaf(gvi, wb.z, acc[6]);
            acc[7]  = fmaf(gvi, wb.w, acc[7]);
            acc[8]  = fmaf(gvi, wc.x, acc[8]);
            acc[9]  = fmaf(gvi, wc.y, acc[9]);
            acc[10] = fmaf(gvi, wc.z, acc[10]);
            acc[11] = fmaf(gvi, wc.w, acc[11]);
            acc[12] = fmaf(gvi, wd.x, acc[12]);
            acc[13] = fmaf(gvi, wd.y, acc[13]);
            acc[14] = fmaf(gvi, wd.z, acc[14]);
            acc[15] = fmaf(gvi, wd.w, acc[15]);
        }
    }

    if (row < n_nodes) {
        float4* orow = (float4*)(out + (size_t)row * 64 + fbase);
        orow[0] = make_float4(acc[0],  acc[1],  acc[2],  acc[3]);
        orow[1] = make_float4(acc[4],  acc[5],  acc[6],  acc[7]);
        orow[2] = make_float4(acc[8],  acc[9],  acc[10], acc[11]);
        orow[3] = make_float4(acc[12], acc[13], acc[14], acc[15]);
    }
}

extern "C" void kernel_launch(void* const* d_in, const int* in_sizes, int n_in,
                              void* d_out, int out_size, void* d_ws, size_t ws_size,
                              hipStream_t stream)
{
    const float* feat   = (const float*)d_in[0];   // [N, 64]
    const float* pseudo = (const float*)d_in[1];   // [E, 2]
    const int*   rowptr = (const int*)d_in[2];     // [N+1]
    const int*   colind = (const int*)d_in[3];     // [E]
    const float* projW  = (const float*)d_in[4];   // [L, 2, 2]
    const float* projB  = (const float*)d_in[5];   // [L, 2]
    const float* fcW    = (const float*)d_in[6];   // [L, 64, 192]
    const float* mu     = (const float*)d_in[7];   // [L, 3, 2]
    const float* isg    = (const float*)d_in[8];   // [L, 3, 2]
    float* out = (float*)d_out;

    int n = in_sizes[0] / FEAT;                         // 50000
    int n_layers = in_sizes[6] / (FEAT * NKERN * FEAT); // 3

    float* gbuf = (float*)d_ws;                    // n * 192 floats
    float* hbuf = gbuf + (size_t)n * NKERN * FEAT; // n * 64 floats

    dim3 blk(256);
    dim3 aggGrid((n + 3) / 4);
    dim3 gemmGrid((n + 63) / 64);

    const float* hin = feat;
    for (int l = 0; l < n_layers; ++l) {
        float* hout = (l == n_layers - 1) ? out : hbuf;
        agg_kernel<<<aggGrid, blk, 0, stream>>>(
            hin, pseudo, rowptr, colind,
            projW + (size_t)l * 4, projB + (size_t)l * 2,
            mu + (size_t)l * 6, isg + (size_t)l * 6,
            gbuf, n);
        gemm_kernel<<<gemmGrid, blk, 0, stream>>>(
            gbuf, fcW + (size_t)l * FEAT * NKERN * FEAT, hout, n);
        hin = hbuf;
    }
}

// Round 4
// 368.665 us; speedup vs baseline: 1.4077x; 1.0062x over previous
//
#include <hip/hip_runtime.h>
#include <math.h>

#define FEAT 64
#define NKERN 3

// Per-edge Gaussian kernel weights for one layer: wbuf[e, k], k=0..2.
__global__ __launch_bounds__(256) void wk_kernel(
    const float* __restrict__ pseudo,  // [E, 2]
    const float* __restrict__ projW,   // [2,2] (din,dout)
    const float* __restrict__ projB,   // [2]
    const float* __restrict__ mu,      // [3,2]
    const float* __restrict__ isg,     // [3,2]
    float* __restrict__ wbuf,          // [E, 3]
    int n_edges)
{
    int e = blockIdx.x * 256 + threadIdx.x;
    if (e >= n_edges) return;
    float2 p = ((const float2*)pseudo)[e];
    float u0 = tanhf(fmaf(p.x, projW[0], fmaf(p.y, projW[2], projB[0])));
    float u1 = tanhf(fmaf(p.x, projW[1], fmaf(p.y, projW[3], projB[1])));
    float d0, d1, s0, s1;
    d0 = u0 - mu[0]; d1 = u1 - mu[1]; s0 = isg[0]; s1 = isg[1];
    float w0 = expf(-0.5f * (d0*d0*s0*s0 + d1*d1*s1*s1));
    d0 = u0 - mu[2]; d1 = u1 - mu[3]; s0 = isg[2]; s1 = isg[3];
    float w1 = expf(-0.5f * (d0*d0*s0*s0 + d1*d1*s1*s1));
    d0 = u0 - mu[4]; d1 = u1 - mu[5]; s0 = isg[4]; s1 = isg[5];
    float w2 = expf(-0.5f * (d0*d0*s0*s0 + d1*d1*s1*s1));
    wbuf[(size_t)e * 3 + 0] = w0;
    wbuf[(size_t)e * 3 + 1] = w1;
    wbuf[(size_t)e * 3 + 2] = w2;
}

// g[n, k*64+j] = sum_{e in row(n)} wbuf[e,k] * h[colind[e], j]
// One wave per node, lane = feature j. colind/wbuf reads are wave-uniform
// (merged s_load_dwordx16 on the scalar pipe); the only VALU work is the
// 32 coalesced gathers + 96 v_fmac with SGPR weight operands.
__global__ __launch_bounds__(256) void agg_kernel(
    const float* __restrict__ h,       // [N, 64]
    const int*   __restrict__ rowptr,  // [N+1]
    const int*   __restrict__ colind,  // [E]
    const float* __restrict__ wbuf,    // [E, 3]
    float* __restrict__ g,             // [N, 192]
    int n_nodes)
{
    int lane = threadIdx.x & 63;
    int node = (int)((blockIdx.x * blockDim.x + threadIdx.x) >> 6);
    if (node >= n_nodes) return;
    int nu  = __builtin_amdgcn_readfirstlane(node);
    int r0  = rowptr[nu];
    int deg = rowptr[nu + 1] - r0;   // fixed 32 in this problem

    float a0 = 0.f, a1 = 0.f, a2 = 0.f;
    if (deg == 32) {
        #pragma unroll
        for (int ch = 0; ch < 2; ++ch) {
            int base = r0 + ch * 16;
            float v[16];
            #pragma unroll
            for (int i = 0; i < 16; ++i) {
                int cc = colind[base + i];              // uniform -> s_load
                v[i] = h[(size_t)cc * FEAT + lane];     // SGPR base + lane off
            }
            #pragma unroll
            for (int i = 0; i < 16; ++i) {
                const float* wp = wbuf + (size_t)(base + i) * 3;  // uniform
                a0 = fmaf(wp[0], v[i], a0);
                a1 = fmaf(wp[1], v[i], a1);
                a2 = fmaf(wp[2], v[i], a2);
            }
        }
    } else {
        for (int i = 0; i < deg; ++i) {
            int cc = colind[r0 + i];
            float vv = h[(size_t)cc * FEAT + lane];
            const float* wp = wbuf + (size_t)(r0 + i) * 3;
            a0 = fmaf(wp[0], vv, a0);
            a1 = fmaf(wp[1], vv, a1);
            a2 = fmaf(wp[2], vv, a2);
        }
    }
    float* gp = g + (size_t)node * (NKERN * FEAT);
    gp[lane]            = a0;
    gp[FEAT + lane]     = a1;
    gp[2 * FEAT + lane] = a2;
}

// out[n, f] = sum_jp g[n, jp] * Wcat[jp, f], Wcat[k*64+j, f] = fcW[j, k*64+f].
// Wcat staged in LDS [192][64]. lane = row; wave w covers f in [16w, 16w+16).
// W reads are wave-uniform ds_read_b128 broadcasts (in-order LDS retire, no
// SMEM/LDS lgkm mixing); g reads are per-lane float4 from L1.
__global__ __launch_bounds__(256) void gemm_kernel(
    const float* __restrict__ g,    // [N, 192]
    const float* __restrict__ fcW,  // [64, 192] this layer
    float* __restrict__ out,        // [N, 64]
    int n_nodes)
{
    __shared__ float Wl[NKERN * FEAT * FEAT];  // [192][64], 48 KB
    int tid = threadIdx.x;
    for (int i = tid; i < 192 * 64; i += 256) {
        int jp = i >> 6, f = i & 63;
        Wl[i] = fcW[(jp & 63) * 192 + (jp >> 6) * 64 + f];
    }
    __syncthreads();

    int lane  = tid & 63;
    int fbase = __builtin_amdgcn_readfirstlane((tid >> 6) * 16);
    int row   = blockIdx.x * 64 + lane;
    int rowc  = row < n_nodes ? row : n_nodes - 1;
    const float4* grow4 = (const float4*)(g + (size_t)rowc * 192);

    float acc[16];
    #pragma unroll
    for (int i = 0; i < 16; ++i) acc[i] = 0.f;

    #pragma unroll 2
    for (int jp4 = 0; jp4 < 48; ++jp4) {
        float4 gv = grow4[jp4];
        const float* wr = &Wl[(jp4 * 4) * 64 + fbase];
        #pragma unroll
        for (int i = 0; i < 4; ++i) {
            float gvi = (i == 0) ? gv.x : (i == 1) ? gv.y : (i == 2) ? gv.z : gv.w;
            float4 wa = *(const float4*)(wr + i * 64 + 0);
            float4 wb = *(const float4*)(wr + i * 64 + 4);
            float4 wc = *(const float4*)(wr + i * 64 + 8);
            float4 wd = *(const float4*)(wr + i * 64 + 12);
            acc[0]  = fmaf(gvi, wa.x, acc[0]);
            acc[1]  = fmaf(gvi, wa.y, acc[1]);
            acc[2]  = fmaf(gvi, wa.z, acc[2]);
            acc[3]  = fmaf(gvi, wa.w, acc[3]);
            acc[4]  = fmaf(gvi, wb.x, acc[4]);
            acc[5]  = fmaf(gvi, wb.y, acc[5]);
            acc[6]  = fmaf(gvi, wb.z, acc[6]);
            acc[7]  = fmaf(gvi, wb.w, acc[7]);
            acc[8]  = fmaf(gvi, wc.x, acc[8]);
            acc[9]  = fmaf(gvi, wc.y, acc[9]);
            acc[10] = fmaf(gvi, wc.z, acc[10]);
            acc[11] = fmaf(gvi, wc.w, acc[11]);
            acc[12] = fmaf(gvi, wd.x, acc[12]);
            acc[13] = fmaf(gvi, wd.y, acc[13]);
            acc[14] = fmaf(gvi, wd.z, acc[14]);
            acc[15] = fmaf(gvi, wd.w, acc[15]);
        }
    }

    if (row < n_nodes) {
        float4* orow = (float4*)(out + (size_t)row * 64 + fbase);
        orow[0] = make_float4(acc[0],  acc[1],  acc[2],  acc[3]);
        orow[1] = make_float4(acc[4],  acc[5],  acc[6],  acc[7]);
        orow[2] = make_float4(acc[8],  acc[9],  acc[10], acc[11]);
        orow[3] = make_float4(acc[12], acc[13], acc[14], acc[15]);
    }
}

extern "C" void kernel_launch(void* const* d_in, const int* in_sizes, int n_in,
                              void* d_out, int out_size, void* d_ws, size_t ws_size,
                              hipStream_t stream)
{
    const float* feat   = (const float*)d_in[0];   // [N, 64]
    const float* pseudo = (const float*)d_in[1];   // [E, 2]
    const int*   rowptr = (const int*)d_in[2];     // [N+1]
    const int*   colind = (const int*)d_in[3];     // [E]
    const float* projW  = (const float*)d_in[4];   // [L, 2, 2]
    const float* projB  = (const float*)d_in[5];   // [L, 2]
    const float* fcW    = (const float*)d_in[6];   // [L, 64, 192]
    const float* mu     = (const float*)d_in[7];   // [L, 3, 2]
    const float* isg    = (const float*)d_in[8];   // [L, 3, 2]
    float* out = (float*)d_out;

    int n = in_sizes[0] / FEAT;                         // 50000
    int e = in_sizes[3];                                // 1.6M
    int n_layers = in_sizes[6] / (FEAT * NKERN * FEAT); // 3

    float* gbuf = (float*)d_ws;                       // n * 192 floats
    float* hbuf = gbuf + (size_t)n * NKERN * FEAT;    // n * 64 floats
    float* wbuf = hbuf + (size_t)n * FEAT;            // e * 3 floats

    dim3 blk(256);
    dim3 wkGrid((e + 255) / 256);
    dim3 aggGrid((n + 3) / 4);
    dim3 gemmGrid((n + 63) / 64);

    const float* hin = feat;
    for (int l = 0; l < n_layers; ++l) {
        float* hout = (l == n_layers - 1) ? out : hbuf;
        wk_kernel<<<wkGrid, blk, 0, stream>>>(
            pseudo, projW + (size_t)l * 4, projB + (size_t)l * 2,
            mu + (size_t)l * 6, isg + (size_t)l * 6, wbuf, e);
        agg_kernel<<<aggGrid, blk, 0, stream>>>(
            hin, rowptr, colind, wbuf, gbuf, n);
        gemm_kernel<<<gemmGrid, blk, 0, stream>>>(
            gbuf, fcW + (size_t)l * FEAT * NKERN * FEAT, hout, n);
        hin = hbuf;
    }
}